// Round 1
// baseline (1183.714 us; speedup 1.0000x reference)
//
#include <hip/hip_runtime.h>
#include <math.h>

// Problem constants (from reference)
#define BATCH   128
#define SEQLEN  8192
#define NFEAT   16
#define DIM     256
#define NCYC    4
#define NSPLIT  8                 // L-chunks per batch row in kernel 1
#define CHUNK   (SEQLEN / NSPLIT) // 1024
#define TPB     256

// DFT bin indices: freqs[k] = k * 30 / 8192; nearest to {1/12, 1/4, 1/2, 1}
// k = round(c * 8192/30): 22.76->23, 68.27->68, 136.53->137, 273.07->273
__device__ __constant__ int c_bins[NCYC] = {23, 68, 137, 273};

// Kernel 1: partial DFT sums. grid = BATCH*NSPLIT blocks, 256 threads.
// Each block handles CHUNK=1024 samples of one batch row, accumulates
// re/im for the 4 bins, writes 8 floats to ws[(b*NSPLIT+s)*8 + j].
__global__ __launch_bounds__(TPB) void dft_partial_kernel(
    const float* __restrict__ x,   // (B, L, NF)
    float* __restrict__ ws)        // (B, NSPLIT, 8)
{
    const int blk = blockIdx.x;
    const int b   = blk / NSPLIT;
    const int s   = blk % NSPLIT;
    const int tid = threadIdx.x;

    const float* base = x + (size_t)b * SEQLEN * NFEAT;
    const int n0 = s * CHUNK;

    float re[NCYC] = {0.f, 0.f, 0.f, 0.f};
    float im[NCYC] = {0.f, 0.f, 0.f, 0.f};

    #pragma unroll
    for (int i = 0; i < CHUNK / TPB; ++i) {
        const int n = n0 + i * TPB + tid;
        const float v = base[(size_t)n * NFEAT];   // stride-16 read, col 0 only
        #pragma unroll
        for (int k = 0; k < NCYC; ++k) {
            // exact integer phase: m = (bin*n) mod 8192, angle = -2*pi*m/8192
            const int m = (c_bins[k] * n) & (SEQLEN - 1);
            const float ang = (float)m * (-6.283185307179586f / (float)SEQLEN);
            float sn, cs;
            __sincosf(ang, &sn, &cs);
            re[k] = fmaf(v, cs, re[k]);
            im[k] = fmaf(v, sn, im[k]);
        }
    }

    // wave (64-lane) shuffle reduction of the 8 accumulators
    #pragma unroll
    for (int k = 0; k < NCYC; ++k) {
        #pragma unroll
        for (int off = 32; off > 0; off >>= 1) {
            re[k] += __shfl_down(re[k], off);
            im[k] += __shfl_down(im[k], off);
        }
    }

    __shared__ float sred[TPB / 64][2 * NCYC];
    const int wave = tid >> 6;
    const int lane = tid & 63;
    if (lane == 0) {
        #pragma unroll
        for (int k = 0; k < NCYC; ++k) {
            sred[wave][2 * k]     = re[k];
            sred[wave][2 * k + 1] = im[k];
        }
    }
    __syncthreads();

    if (tid < 2 * NCYC) {
        float sum = 0.f;
        #pragma unroll
        for (int w = 0; w < TPB / 64; ++w) sum += sred[w][tid];
        ws[((size_t)b * NSPLIT + s) * (2 * NCYC) + tid] = sum;
    }
}

// Kernel 2: finalize. grid = BATCH blocks, 256 threads (one per output dim).
// Every thread redundantly reduces the 8*NSPLIT=64 partials (L2-cached
// broadcast), forms weighted [mag0,ph0,...,mag3,ph3], then computes one
// element of feats @ proj_w.T + proj_b.
__global__ __launch_bounds__(TPB) void finalize_kernel(
    const float* __restrict__ ws,      // (B, NSPLIT, 8)
    const float* __restrict__ cw,      // (NC,)
    const float* __restrict__ pw,      // (D, 2*NC) row-major
    const float* __restrict__ pb,      // (D,)
    float* __restrict__ out)           // (B, D)
{
    const int b = blockIdx.x;
    const int d = threadIdx.x;
    const float* wsb = ws + (size_t)b * NSPLIT * (2 * NCYC);

    float fw[2 * NCYC];
    #pragma unroll
    for (int k = 0; k < NCYC; ++k) {
        float re = 0.f, im = 0.f;
        #pragma unroll
        for (int s = 0; s < NSPLIT; ++s) {
            re += wsb[s * (2 * NCYC) + 2 * k];
            im += wsb[s * (2 * NCYC) + 2 * k + 1];
        }
        const float mag = sqrtf(re * re + im * im);
        const float ph  = atan2f(im, re);
        const float w   = cw[k];
        fw[2 * k]     = mag * w;
        fw[2 * k + 1] = ph * w;
    }

    float acc = pb[d];
    #pragma unroll
    for (int j = 0; j < 2 * NCYC; ++j)
        acc = fmaf(fw[j], pw[d * (2 * NCYC) + j], acc);

    out[(size_t)b * DIM + d] = acc;
}

extern "C" void kernel_launch(void* const* d_in, const int* in_sizes, int n_in,
                              void* d_out, int out_size, void* d_ws, size_t ws_size,
                              hipStream_t stream) {
    const float* input_sequence = (const float*)d_in[0]; // (128, 8192, 16)
    // d_in[1] = hidden_states — UNUSED by the reference (1 GB, do not touch)
    const float* cycle_weights  = (const float*)d_in[2]; // (4,)
    const float* proj_w         = (const float*)d_in[3]; // (256, 8)
    const float* proj_b         = (const float*)d_in[4]; // (256,)
    float* out = (float*)d_out;                          // (128, 256)
    float* ws  = (float*)d_ws;                           // BATCH*NSPLIT*8 floats = 32 KB

    dft_partial_kernel<<<BATCH * NSPLIT, TPB, 0, stream>>>(input_sequence, ws);
    finalize_kernel<<<BATCH, TPB, 0, stream>>>(ws, cycle_weights, proj_w, proj_b, out);
}

// Round 2
// 1179.430 us; speedup vs baseline: 1.0036x; 1.0036x over previous
//
#include <hip/hip_runtime.h>
#include <math.h>

// Problem constants (from reference)
#define BATCH   128
#define SEQLEN  8192
#define NFEAT   16
#define DIM     256
#define NCYC    4
#define NSPLIT  16                // L-chunks per batch row in kernel 1
#define CHUNK   (SEQLEN / NSPLIT) // 512
#define TPB     256

// DFT bin indices: freqs[k] = k * 30 / 8192; nearest to {1/12, 1/4, 1/2, 1}
// k = round(c * 8192/30): 22.76->23, 68.27->68, 136.53->137, 273.07->273
__device__ __constant__ int c_bins[NCYC] = {23, 68, 137, 273};

// Kernel 1: partial DFT sums. grid = BATCH*NSPLIT blocks, 256 threads.
// Each block handles CHUNK samples of one batch row, accumulates re/im
// for the 4 bins, writes 8 floats to ws[(b*NSPLIT+s)*8 + j].
// Memory pattern: 1 dword per 64 B line; every line of the 64 MB input is
// touched exactly once — fetch-optimal, nothing to vectorize.
__global__ __launch_bounds__(TPB) void dft_partial_kernel(
    const float* __restrict__ x,   // (B, L, NF)
    float* __restrict__ ws)        // (B, NSPLIT, 8)
{
    const int blk = blockIdx.x;
    const int b   = blk / NSPLIT;
    const int s   = blk % NSPLIT;
    const int tid = threadIdx.x;

    const float* base = x + (size_t)b * SEQLEN * NFEAT;
    const int n0 = s * CHUNK;

    float re[NCYC] = {0.f, 0.f, 0.f, 0.f};
    float im[NCYC] = {0.f, 0.f, 0.f, 0.f};

    #pragma unroll
    for (int i = 0; i < CHUNK / TPB; ++i) {
        const int n = n0 + i * TPB + tid;
        const float v = base[(size_t)n * NFEAT];   // stride-16 read, col 0 only
        #pragma unroll
        for (int k = 0; k < NCYC; ++k) {
            // exact integer phase: m = (bin*n) mod 8192, angle = -2*pi*m/8192
            const int m = (c_bins[k] * n) & (SEQLEN - 1);
            const float ang = (float)m * (-6.283185307179586f / (float)SEQLEN);
            float sn, cs;
            __sincosf(ang, &sn, &cs);
            re[k] = fmaf(v, cs, re[k]);
            im[k] = fmaf(v, sn, im[k]);
        }
    }

    // wave (64-lane) shuffle reduction of the 8 accumulators
    #pragma unroll
    for (int k = 0; k < NCYC; ++k) {
        #pragma unroll
        for (int off = 32; off > 0; off >>= 1) {
            re[k] += __shfl_down(re[k], off);
            im[k] += __shfl_down(im[k], off);
        }
    }

    __shared__ float sred[TPB / 64][2 * NCYC];
    const int wave = tid >> 6;
    const int lane = tid & 63;
    if (lane == 0) {
        #pragma unroll
        for (int k = 0; k < NCYC; ++k) {
            sred[wave][2 * k]     = re[k];
            sred[wave][2 * k + 1] = im[k];
        }
    }
    __syncthreads();

    if (tid < 2 * NCYC) {
        float sum = 0.f;
        #pragma unroll
        for (int w = 0; w < TPB / 64; ++w) sum += sred[w][tid];
        ws[((size_t)b * NSPLIT + s) * (2 * NCYC) + tid] = sum;
    }
}

// Kernel 2: finalize. grid = BATCH blocks, 256 threads (one per output dim).
// Every thread redundantly reduces the NSPLIT partials (L2-cached broadcast),
// forms weighted [mag0,ph0,...,mag3,ph3], then computes one element of
// feats @ proj_w.T + proj_b.
__global__ __launch_bounds__(TPB) void finalize_kernel(
    const float* __restrict__ ws,      // (B, NSPLIT, 8)
    const float* __restrict__ cw,      // (NC,)
    const float* __restrict__ pw,      // (D, 2*NC) row-major
    const float* __restrict__ pb,      // (D,)
    float* __restrict__ out)           // (B, D)
{
    const int b = blockIdx.x;
    const int d = threadIdx.x;
    const float* wsb = ws + (size_t)b * NSPLIT * (2 * NCYC);

    float fw[2 * NCYC];
    #pragma unroll
    for (int k = 0; k < NCYC; ++k) {
        float re = 0.f, im = 0.f;
        #pragma unroll
        for (int s = 0; s < NSPLIT; ++s) {
            re += wsb[s * (2 * NCYC) + 2 * k];
            im += wsb[s * (2 * NCYC) + 2 * k + 1];
        }
        const float mag = sqrtf(re * re + im * im);
        const float ph  = atan2f(im, re);
        const float w   = cw[k];
        fw[2 * k]     = mag * w;
        fw[2 * k + 1] = ph * w;
    }

    float acc = pb[d];
    #pragma unroll
    for (int j = 0; j < 2 * NCYC; ++j)
        acc = fmaf(fw[j], pw[d * (2 * NCYC) + j], acc);

    out[(size_t)b * DIM + d] = acc;
}

extern "C" void kernel_launch(void* const* d_in, const int* in_sizes, int n_in,
                              void* d_out, int out_size, void* d_ws, size_t ws_size,
                              hipStream_t stream) {
    const float* input_sequence = (const float*)d_in[0]; // (128, 8192, 16)
    // d_in[1] = hidden_states — UNUSED by the reference (1 GB, do not touch)
    const float* cycle_weights  = (const float*)d_in[2]; // (4,)
    const float* proj_w         = (const float*)d_in[3]; // (256, 8)
    const float* proj_b         = (const float*)d_in[4]; // (256,)
    float* out = (float*)d_out;                          // (128, 256)
    float* ws  = (float*)d_ws;                           // BATCH*NSPLIT*8 floats = 64 KB

    dft_partial_kernel<<<BATCH * NSPLIT, TPB, 0, stream>>>(input_sequence, ws);
    finalize_kernel<<<BATCH, TPB, 0, stream>>>(ws, cycle_weights, proj_w, proj_b, out);
}